// Round 1
// baseline (398.364 us; speedup 1.0000x reference)
//
#include <hip/hip_runtime.h>
#include <hip/hip_bf16.h>

// Problem constants
#define VSZ 32000
#define DSZ 256
#define BSZ 32
#define MSZ 1024
#define TSZ 4
#define PSZ 1025              // pos table rows (MAXS+1)
#define HOPS 3
#define VD (VSZ * DSZ)

// Workspace layout (float offsets)
#define OFF_POS   0                        // int[B*M] positions
#define OFF_U     (BSZ * MSZ)              // 32768: float[B*D] u
#define OFF_U0    (OFF_U + BSZ * DSZ)      // float[B*D] u0
#define OFF_OK0   (OFF_U0 + BSZ * DSZ)     // float[B*D] o_k of hop 0
#define OFF_PROJ  (OFF_OK0 + BSZ * DSZ)    // float[V*B] proj
#define OFF_PP    (OFF_PROJ + VSZ * BSZ)   // float[P*B] posproj
#define OFF_SC    (OFF_PP + PSZ * BSZ)     // float[B*M] scores
#define OFF_PROB  (OFF_SC + BSZ * MSZ)     // float[B*M] prob
#define OFF_PART  (OFF_PROB + BSZ * MSZ)   // float[8*B*D] o_k partials

// Output layout (floats): prob_lg [B,M] | p_vocab [B,V] | hidden [1,B,D]
#define OUT_PV    (BSZ * MSZ)
#define OUT_HID   (OUT_PV + BSZ * VSZ)

// ---------------------------------------------------------------------------
// K1: positions[b][m] = pad ? 0 : inclusive-cumsum over m of (story[m][b][0]!=0)
__global__ void k_positions(const int* __restrict__ story, int* __restrict__ pos) {
    int b = blockIdx.x;
    int m = threadIdx.x;   // 1024 threads
    __shared__ int sc[MSZ];
    int tok0 = story[(m * BSZ + b) * TSZ + 0];
    int flag = (tok0 != 0) ? 1 : 0;
    sc[m] = flag;
    __syncthreads();
    // Hillis-Steele inclusive scan
    for (int off = 1; off < MSZ; off <<= 1) {
        int v = (m >= off) ? sc[m - off] : 0;
        __syncthreads();
        sc[m] += v;
        __syncthreads();
    }
    pos[b * MSZ + m] = flag ? sc[m] : 0;
}

// ---------------------------------------------------------------------------
// K2: GRU step. One block per b, 256 threads (one per d).
__global__ void k_gru(const int* __restrict__ enc_query,
                      const float* __restrict__ last_hidden,
                      const float* __restrict__ C0,
                      const float* __restrict__ w_ih, const float* __restrict__ w_hh,
                      const float* __restrict__ b_ih, const float* __restrict__ b_hh,
                      float* __restrict__ u, float* __restrict__ u0,
                      float* __restrict__ hidden_out) {
    int b = blockIdx.x;
    int d = threadIdx.x;
    __shared__ float xs[DSZ], hs[DSZ];
    int q = enc_query[b];
    xs[d] = C0[(size_t)q * DSZ + d];
    hs[d] = last_hidden[b * DSZ + d];
    __syncthreads();
    float gi[3], gh[3];
#pragma unroll
    for (int g = 0; g < 3; ++g) {
        const float* wi = w_ih + (size_t)(g * DSZ + d) * DSZ;
        const float* wh = w_hh + (size_t)(g * DSZ + d) * DSZ;
        float a = 0.f, c = 0.f;
        for (int j = 0; j < DSZ; j += 4) {
            float4 wv = *(const float4*)(wi + j);
            a += wv.x * xs[j] + wv.y * xs[j + 1] + wv.z * xs[j + 2] + wv.w * xs[j + 3];
            float4 hv = *(const float4*)(wh + j);
            c += hv.x * hs[j] + hv.y * hs[j + 1] + hv.z * hs[j + 2] + hv.w * hs[j + 3];
        }
        gi[g] = a + b_ih[g * DSZ + d];
        gh[g] = c + b_hh[g * DSZ + d];
    }
    float r = 1.f / (1.f + expf(-(gi[0] + gh[0])));
    float z = 1.f / (1.f + expf(-(gi[1] + gh[1])));
    float n = tanhf(gi[2] + r * gh[2]);
    float hn = (1.f - z) * n + z * hs[d];
    int idx = b * DSZ + d;
    u[idx] = hn;
    u0[idx] = hn;
    hidden_out[idx] = hn;
}

// ---------------------------------------------------------------------------
// K_posproj: pp[p][b] = dot(pos_table[p], u[b])   (u = h_new at hop 0)
__global__ void k_posproj(const float* __restrict__ pos_table,
                          const float* __restrict__ u, float* __restrict__ pp) {
    int idx = blockIdx.x * 256 + threadIdx.x;
    if (idx >= PSZ * BSZ) return;
    int p = idx >> 5;
    int b = idx & 31;
    const float* row = pos_table + (size_t)p * DSZ;
    const float* ub = u + b * DSZ;
    float acc = 0.f;
    for (int j = 0; j < DSZ; j += 4) {
        float4 rv = *(const float4*)(row + j);
        float4 uv = *(const float4*)(ub + j);
        acc += rv.x * uv.x + rv.y * uv.y + rv.z * uv.z + rv.w * uv.w;
    }
    pp[idx] = acc;
}

// ---------------------------------------------------------------------------
// K3: proj[v][b] = dot(C[h][v], u[b]).  Block = 256 v-rows; thread tile 4v x 8b.
__global__ __launch_bounds__(256) void k_proj(const float* __restrict__ Ct,
                                              const float* __restrict__ u,
                                              float* __restrict__ proj) {
    __shared__ float uL[BSZ * DSZ];   // 32 KB
    int t = threadIdx.x;
    for (int i = t; i < BSZ * DSZ; i += 256) uL[i] = u[i];
    __syncthreads();
    int vq = t & 63, bg = t >> 6;
    int v0 = blockIdx.x * 256 + vq * 4;
    int b0 = bg * 8;
    float acc[4][8] = {};
    for (int c = 0; c < DSZ; c += 4) {
        float4 w0 = *(const float4*)(Ct + (size_t)(v0 + 0) * DSZ + c);
        float4 w1 = *(const float4*)(Ct + (size_t)(v0 + 1) * DSZ + c);
        float4 w2 = *(const float4*)(Ct + (size_t)(v0 + 2) * DSZ + c);
        float4 w3 = *(const float4*)(Ct + (size_t)(v0 + 3) * DSZ + c);
#pragma unroll
        for (int j = 0; j < 8; ++j) {
            float4 uv = *(const float4*)(&uL[(b0 + j) * DSZ + c]);
            acc[0][j] += w0.x * uv.x + w0.y * uv.y + w0.z * uv.z + w0.w * uv.w;
            acc[1][j] += w1.x * uv.x + w1.y * uv.y + w1.z * uv.z + w1.w * uv.w;
            acc[2][j] += w2.x * uv.x + w2.y * uv.y + w2.z * uv.z + w2.w * uv.w;
            acc[3][j] += w3.x * uv.x + w3.y * uv.y + w3.z * uv.z + w3.w * uv.w;
        }
    }
#pragma unroll
    for (int i = 0; i < 4; ++i)
#pragma unroll
        for (int j = 0; j < 8; ++j)
            proj[(size_t)(v0 + i) * BSZ + (b0 + j)] = acc[i][j];
}

// ---------------------------------------------------------------------------
// K4: scores[b][m] = sum_t proj[s[b][m][t]][b] (+ pp[pos][b] at hop 0)
__global__ void k_scores(const int* __restrict__ story, const int* __restrict__ pos,
                         const float* __restrict__ proj, const float* __restrict__ pp,
                         float* __restrict__ scores, float* __restrict__ outlg,
                         int hop) {
    int idx = blockIdx.x * 256 + threadIdx.x;   // b*M + m
    int b = idx >> 10;
    int m = idx & (MSZ - 1);
    const int* st = story + (m * BSZ + b) * TSZ;
    float s = proj[(size_t)st[0] * BSZ + b] + proj[(size_t)st[1] * BSZ + b] +
              proj[(size_t)st[2] * BSZ + b] + proj[(size_t)st[3] * BSZ + b];
    if (hop == 0) s += pp[pos[idx] * BSZ + b];
    scores[idx] = s;
    if (hop == 2) outlg[idx] = s;
}

// ---------------------------------------------------------------------------
// K5: softmax over m per b. 1 block per b, 1024 threads (16 waves).
__global__ void k_softmax(const float* __restrict__ scores, float* __restrict__ prob) {
    int b = blockIdx.x;
    int m = threadIdx.x;
    __shared__ float red[16];
    float v = scores[b * MSZ + m];
    float mx = v;
#pragma unroll
    for (int o = 32; o > 0; o >>= 1) mx = fmaxf(mx, __shfl_xor(mx, o, 64));
    int wid = m >> 6, lane = m & 63;
    if (lane == 0) red[wid] = mx;
    __syncthreads();
    if (m == 0) {
        float a = red[0];
        for (int i = 1; i < 16; ++i) a = fmaxf(a, red[i]);
        red[0] = a;
    }
    __syncthreads();
    float bm = red[0];
    __syncthreads();
    float e = expf(v - bm);
    float sm = e;
#pragma unroll
    for (int o = 32; o > 0; o >>= 1) sm += __shfl_xor(sm, o, 64);
    if (lane == 0) red[wid] = sm;
    __syncthreads();
    if (m == 0) {
        float a = 0.f;
        for (int i = 0; i < 16; ++i) a += red[i];
        red[0] = a;
    }
    __syncthreads();
    prob[b * MSZ + m] = e / red[0];
}

// ---------------------------------------------------------------------------
// K6: o_k partials. Grid (8 m-chunks, 32 b), 256 threads (one per d).
__global__ __launch_bounds__(256) void k_okpart(const int* __restrict__ story,
                                                const float* __restrict__ prob,
                                                const float* __restrict__ Ct,
                                                float* __restrict__ part) {
    int mc = blockIdx.x;
    int b = blockIdx.y;
    int d = threadIdx.x;
    float acc = 0.f;
    for (int mm = 0; mm < MSZ / 8; ++mm) {
        int m = mc * (MSZ / 8) + mm;
        float pw = prob[b * MSZ + m];
        const int* st = story + (m * BSZ + b) * TSZ;
        int t0 = st[0], t1 = st[1], t2 = st[2], t3 = st[3];
        acc += pw * (Ct[(size_t)t0 * DSZ + d] + Ct[(size_t)t1 * DSZ + d] +
                     Ct[(size_t)t2 * DSZ + d] + Ct[(size_t)t3 * DSZ + d]);
    }
    part[(mc * BSZ + b) * DSZ + d] = acc;
}

// K7: reduce partials -> o_k; u += o_k; optionally save o_k (hop 0).
__global__ void k_okreduce(const float* __restrict__ part, float* __restrict__ u,
                           float* __restrict__ ok0, int save0) {
    int idx = blockIdx.x * 256 + threadIdx.x;   // B*D = 8192
    float s = 0.f;
#pragma unroll
    for (int c = 0; c < 8; ++c) s += part[c * BSZ * DSZ + idx];
    if (save0) ok0[idx] = s;
    u[idx] += s;
}

// ---------------------------------------------------------------------------
// K8: p_vocab[b][v] = dot(W1_w[v], concat(u0[b], ok0[b])) + W1_b[v]
__global__ __launch_bounds__(256) void k_pvocab(const float* __restrict__ u0,
                                                const float* __restrict__ ok0,
                                                const float* __restrict__ W1w,
                                                const float* __restrict__ W1b,
                                                float* __restrict__ out_pv) {
    __shared__ float catL[BSZ * 2 * DSZ];   // 64 KB
    int t = threadIdx.x;
    for (int i = t; i < BSZ * DSZ; i += 256) {
        int b = i >> 8, d = i & 255;
        catL[b * 512 + d] = u0[i];
        catL[b * 512 + 256 + d] = ok0[i];
    }
    __syncthreads();
    int vq = t & 63, bg = t >> 6;
    int v0 = blockIdx.x * 256 + vq * 4;
    int b0 = bg * 8;
    float acc[4][8] = {};
    for (int c = 0; c < 2 * DSZ; c += 4) {
        float4 w0 = *(const float4*)(W1w + (size_t)(v0 + 0) * 512 + c);
        float4 w1 = *(const float4*)(W1w + (size_t)(v0 + 1) * 512 + c);
        float4 w2 = *(const float4*)(W1w + (size_t)(v0 + 2) * 512 + c);
        float4 w3 = *(const float4*)(W1w + (size_t)(v0 + 3) * 512 + c);
#pragma unroll
        for (int j = 0; j < 8; ++j) {
            float4 uv = *(const float4*)(&catL[(b0 + j) * 512 + c]);
            acc[0][j] += w0.x * uv.x + w0.y * uv.y + w0.z * uv.z + w0.w * uv.w;
            acc[1][j] += w1.x * uv.x + w1.y * uv.y + w1.z * uv.z + w1.w * uv.w;
            acc[2][j] += w2.x * uv.x + w2.y * uv.y + w2.z * uv.z + w2.w * uv.w;
            acc[3][j] += w3.x * uv.x + w3.y * uv.y + w3.z * uv.z + w3.w * uv.w;
        }
    }
#pragma unroll
    for (int i = 0; i < 4; ++i) {
        float bias = W1b[v0 + i];
#pragma unroll
        for (int j = 0; j < 8; ++j)
            out_pv[(size_t)(b0 + j) * VSZ + (v0 + i)] = acc[i][j] + bias;
    }
}

// ---------------------------------------------------------------------------
extern "C" void kernel_launch(void* const* d_in, const int* in_sizes, int n_in,
                              void* d_out, int out_size, void* d_ws, size_t ws_size,
                              hipStream_t stream) {
    const int*   story   = (const int*)d_in[0];
    const int*   encq    = (const int*)d_in[1];
    const float* lasth   = (const float*)d_in[2];
    const float* C       = (const float*)d_in[3];
    const float* postab  = (const float*)d_in[4];
    const float* W1w     = (const float*)d_in[5];
    const float* W1b     = (const float*)d_in[6];
    const float* gwih    = (const float*)d_in[7];
    const float* gwhh    = (const float*)d_in[8];
    const float* gbih    = (const float*)d_in[9];
    const float* gbhh    = (const float*)d_in[10];

    float* out = (float*)d_out;
    float* wsf = (float*)d_ws;
    int*   pos = (int*)d_ws;                 // OFF_POS
    float* u    = wsf + OFF_U;
    float* u0   = wsf + OFF_U0;
    float* ok0  = wsf + OFF_OK0;
    float* proj = wsf + OFF_PROJ;
    float* pp   = wsf + OFF_PP;
    float* sc   = wsf + OFF_SC;
    float* prob = wsf + OFF_PROB;
    float* part = wsf + OFF_PART;

    k_positions<<<BSZ, MSZ, 0, stream>>>(story, pos);
    k_gru<<<BSZ, DSZ, 0, stream>>>(encq, lasth, C, gwih, gwhh, gbih, gbhh,
                                   u, u0, out + OUT_HID);
    k_posproj<<<(PSZ * BSZ + 255) / 256, 256, 0, stream>>>(postab, u, pp);

    for (int hop = 0; hop < HOPS; ++hop) {
        k_proj<<<VSZ / 256, 256, 0, stream>>>(C + (size_t)hop * VD, u, proj);
        k_scores<<<BSZ * MSZ / 256, 256, 0, stream>>>(story, pos, proj, pp, sc, out, hop);
        k_softmax<<<BSZ, MSZ, 0, stream>>>(sc, prob);
        k_okpart<<<dim3(8, BSZ), 256, 0, stream>>>(story, prob,
                                                   C + (size_t)(hop + 1) * VD, part);
        k_okreduce<<<BSZ * DSZ / 256, 256, 0, stream>>>(part, u, ok0, hop == 0 ? 1 : 0);
        if (hop == 0) {
            k_pvocab<<<VSZ / 256, 256, 0, stream>>>(u0, ok0, W1w, W1b, out + OUT_PV);
        }
    }
}

// Round 2
// 301.409 us; speedup vs baseline: 1.3217x; 1.3217x over previous
//
#include <hip/hip_runtime.h>
#include <hip/hip_bf16.h>

#define VSZ 32000
#define DSZ 256
#define BSZ 32
#define MSZ 1024
#define TSZ 4
#define PSZ 1025
#define HOPS 3
#define VD (VSZ * DSZ)
#define PVN (BSZ * VSZ)          // 1,024,000

// Workspace layout (float offsets)
#define OFF_POS   0                         // int[B*M]
#define OFF_U     32768
#define OFF_U0    40960
#define OFF_OK0   49152
#define OFF_PP    57344                     // 1025*32 = 32800
#define OFF_PROB  90144                     // 32768
#define OFF_PART  122912                    // 32*B*D = 262144
#define OFF_PROJA 385056                    // V*B = 1024000
#define OFF_PROJB 1409056                   // V*B (big path only)
#define OFF_PVP   2433056                   // 3*V*B (big path only)
#define END_BIG   5505056
#define END_SMALL 1409056

// Output layout (floats): prob_lg [B,M] | p_vocab [B,V] | hidden [1,B,D]
#define OUT_PV    (BSZ * MSZ)
#define OUT_HID   (OUT_PV + BSZ * VSZ)

// ---------------------------------------------------------------------------
// positions: ballot-based segmented scan. 32 blocks x 1024 threads.
__global__ void k_positions(const int* __restrict__ story, int* __restrict__ pos) {
    int b = blockIdx.x;
    int m = threadIdx.x;
    __shared__ int wsum[16];
    int tok0 = story[(m * BSZ + b) * TSZ];
    int flag = (tok0 != 0) ? 1 : 0;
    unsigned long long mask = __ballot(flag);
    int lane = m & 63, wid = m >> 6;
    int pfx = __popcll(mask & ((1ULL << lane) - 1ULL));
    if (lane == 63) wsum[wid] = pfx + flag;
    __syncthreads();
    if (m == 0) {
        int run = 0;
        for (int i = 0; i < 16; ++i) { int v = wsum[i]; wsum[i] = run; run += v; }
    }
    __syncthreads();
    int incl = wsum[wid] + pfx + flag;
    pos[b * MSZ + m] = flag ? incl : 0;
}

// ---------------------------------------------------------------------------
// GRU step. One block per b, 256 threads (one per d).
__global__ void k_gru(const int* __restrict__ enc_query,
                      const float* __restrict__ last_hidden,
                      const float* __restrict__ C0,
                      const float* __restrict__ w_ih, const float* __restrict__ w_hh,
                      const float* __restrict__ b_ih, const float* __restrict__ b_hh,
                      float* __restrict__ u, float* __restrict__ u0,
                      float* __restrict__ hidden_out) {
    int b = blockIdx.x;
    int d = threadIdx.x;
    __shared__ float xs[DSZ], hs[DSZ];
    int q = enc_query[b];
    xs[d] = C0[(size_t)q * DSZ + d];
    hs[d] = last_hidden[b * DSZ + d];
    __syncthreads();
    float gi[3], gh[3];
#pragma unroll
    for (int g = 0; g < 3; ++g) {
        const float* wi = w_ih + (size_t)(g * DSZ + d) * DSZ;
        const float* wh = w_hh + (size_t)(g * DSZ + d) * DSZ;
        float a = 0.f, c = 0.f;
        for (int j = 0; j < DSZ; j += 4) {
            float4 wv = *(const float4*)(wi + j);
            a += wv.x * xs[j] + wv.y * xs[j + 1] + wv.z * xs[j + 2] + wv.w * xs[j + 3];
            float4 hv = *(const float4*)(wh + j);
            c += hv.x * hs[j] + hv.y * hs[j + 1] + hv.z * hs[j + 2] + hv.w * hs[j + 3];
        }
        gi[g] = a + b_ih[g * DSZ + d];
        gh[g] = c + b_hh[g * DSZ + d];
    }
    float r = 1.f / (1.f + expf(-(gi[0] + gh[0])));
    float z = 1.f / (1.f + expf(-(gi[1] + gh[1])));
    float n = tanhf(gi[2] + r * gh[2]);
    float hn = (1.f - z) * n + z * hs[d];
    int idx = b * DSZ + d;
    u[idx] = hn;
    u0[idx] = hn;
    hidden_out[idx] = hn;
}

// ---------------------------------------------------------------------------
// pp[p][b] = dot(pos_table[p], u[b])
__global__ void k_posproj(const float* __restrict__ pos_table,
                          const float* __restrict__ u, float* __restrict__ pp) {
    int idx = blockIdx.x * 256 + threadIdx.x;
    if (idx >= PSZ * BSZ) return;
    int p = idx >> 5;
    int b = idx & 31;
    const float* row = pos_table + (size_t)p * DSZ;
    const float* ub = u + b * DSZ;
    float acc = 0.f;
    for (int j = 0; j < DSZ; j += 4) {
        float4 rv = *(const float4*)(row + j);
        float4 uv = *(const float4*)(ub + j);
        acc += rv.x * uv.x + rv.y * uv.y + rv.z * uv.z + rv.w * uv.w;
    }
    pp[idx] = acc;
}

// ---------------------------------------------------------------------------
// proj[v][b] = dot(C[h][v], u[b]), split over c by blockIdx.y.
// 256 threads, thread tile 4v x 8b, VT=256 rows per block.
__global__ __launch_bounds__(256) void k_proj2(const float* __restrict__ Ct,
                                               const float* __restrict__ u,
                                               float* __restrict__ destA,
                                               float* __restrict__ destB,
                                               int cshift) {
    int CPB = 1 << cshift;                     // 128 (S=2) or 256 (S=1)
    int c0 = blockIdx.y << cshift;
    float* dest = (blockIdx.y == 0) ? destA : destB;
    __shared__ float uL[BSZ * 256];
    int t = threadIdx.x;
    for (int i = t; i < BSZ * CPB; i += 256) {
        int b = i >> cshift, c = i & (CPB - 1);
        uL[b * CPB + c] = u[b * DSZ + c0 + c];
    }
    __syncthreads();
    int vq = t & 63, bg = t >> 6;
    int v0 = blockIdx.x * 256 + vq * 4;
    int b0 = bg * 8;
    float acc[4][8] = {};
    for (int c = 0; c < CPB; c += 4) {
        float4 w0 = *(const float4*)(Ct + (size_t)(v0 + 0) * DSZ + c0 + c);
        float4 w1 = *(const float4*)(Ct + (size_t)(v0 + 1) * DSZ + c0 + c);
        float4 w2 = *(const float4*)(Ct + (size_t)(v0 + 2) * DSZ + c0 + c);
        float4 w3 = *(const float4*)(Ct + (size_t)(v0 + 3) * DSZ + c0 + c);
#pragma unroll
        for (int j = 0; j < 8; ++j) {
            float4 uv = *(const float4*)(&uL[(b0 + j) * CPB + c]);
            acc[0][j] += w0.x * uv.x + w0.y * uv.y + w0.z * uv.z + w0.w * uv.w;
            acc[1][j] += w1.x * uv.x + w1.y * uv.y + w1.z * uv.z + w1.w * uv.w;
            acc[2][j] += w2.x * uv.x + w2.y * uv.y + w2.z * uv.z + w2.w * uv.w;
            acc[3][j] += w3.x * uv.x + w3.y * uv.y + w3.z * uv.z + w3.w * uv.w;
        }
    }
#pragma unroll
    for (int i = 0; i < 4; ++i) {
        float4 lo = make_float4(acc[i][0], acc[i][1], acc[i][2], acc[i][3]);
        float4 hi = make_float4(acc[i][4], acc[i][5], acc[i][6], acc[i][7]);
        *(float4*)(dest + (size_t)(v0 + i) * BSZ + b0) = lo;
        *(float4*)(dest + (size_t)(v0 + i) * BSZ + b0 + 4) = hi;
    }
}

// ---------------------------------------------------------------------------
// Fused scores (+positional at hop0) + softmax. 32 blocks x 1024 threads.
__global__ void k_attend(const int* __restrict__ story, const int* __restrict__ pos,
                         const float* __restrict__ projA, const float* __restrict__ projB,
                         const float* __restrict__ pp, float* __restrict__ prob,
                         float* __restrict__ outlg, int S, int hop, int do_sm) {
    int b = blockIdx.x;
    int m = threadIdx.x;
    __shared__ float red[16];
    int4 st = *(const int4*)&story[(m * BSZ + b) * TSZ];
    float s = projA[(size_t)st.x * BSZ + b] + projA[(size_t)st.y * BSZ + b] +
              projA[(size_t)st.z * BSZ + b] + projA[(size_t)st.w * BSZ + b];
    if (S == 2)
        s += projB[(size_t)st.x * BSZ + b] + projB[(size_t)st.y * BSZ + b] +
             projB[(size_t)st.z * BSZ + b] + projB[(size_t)st.w * BSZ + b];
    if (hop == 0) s += pp[pos[b * MSZ + m] * BSZ + b];
    if (hop == 2) { outlg[b * MSZ + m] = s; return; }
    // softmax over m
    float mx = s;
#pragma unroll
    for (int o = 32; o > 0; o >>= 1) mx = fmaxf(mx, __shfl_xor(mx, o, 64));
    int wid = m >> 6, lane = m & 63;
    if (lane == 0) red[wid] = mx;
    __syncthreads();
    if (m == 0) {
        float a = red[0];
        for (int i = 1; i < 16; ++i) a = fmaxf(a, red[i]);
        red[0] = a;
    }
    __syncthreads();
    float bm = red[0];
    __syncthreads();
    float e = expf(s - bm);
    float sm = e;
#pragma unroll
    for (int o = 32; o > 0; o >>= 1) sm += __shfl_xor(sm, o, 64);
    if (lane == 0) red[wid] = sm;
    __syncthreads();
    if (m == 0) {
        float a = 0.f;
        for (int i = 0; i < 16; ++i) a += red[i];
        red[0] = a;
    }
    __syncthreads();
    prob[b * MSZ + m] = e / red[0];
}

// ---------------------------------------------------------------------------
// o_k partials: grid (8 mc, 32 b), 256 thr = 64 d-quads x 4 m-subgroups.
__global__ __launch_bounds__(256) void k_okpart2(const int* __restrict__ story,
                                                 const float* __restrict__ prob,
                                                 const float* __restrict__ Ct,
                                                 float* __restrict__ part) {
    int mc = blockIdx.x;
    int b = blockIdx.y;
    int dl = threadIdx.x & 63;
    int ms = threadIdx.x >> 6;
    int mbase = mc * 128 + ms * 32;
    float4 acc = make_float4(0.f, 0.f, 0.f, 0.f);
    for (int i = 0; i < 32; ++i) {
        int m = mbase + i;
        float pw = prob[b * MSZ + m];
        int4 st = *(const int4*)&story[(m * BSZ + b) * TSZ];
        float4 r0 = *(const float4*)&Ct[(size_t)st.x * DSZ + dl * 4];
        float4 r1 = *(const float4*)&Ct[(size_t)st.y * DSZ + dl * 4];
        float4 r2 = *(const float4*)&Ct[(size_t)st.z * DSZ + dl * 4];
        float4 r3 = *(const float4*)&Ct[(size_t)st.w * DSZ + dl * 4];
        acc.x += pw * (r0.x + r1.x + r2.x + r3.x);
        acc.y += pw * (r0.y + r1.y + r2.y + r3.y);
        acc.z += pw * (r0.z + r1.z + r2.z + r3.z);
        acc.w += pw * (r0.w + r1.w + r2.w + r3.w);
    }
    int chunk = mc * 4 + ms;
    *(float4*)&part[((chunk * BSZ) + b) * DSZ + dl * 4] = acc;
}

// reduce 32 partial chunks -> o_k; u += o_k; save ok0 at hop 0.
__global__ void k_okreduce2(const float* __restrict__ part, float* __restrict__ u,
                            float* __restrict__ ok0, int save0) {
    int idx = blockIdx.x * 256 + threadIdx.x;   // B*D = 8192
    float s = 0.f;
#pragma unroll
    for (int c = 0; c < 32; ++c) s += part[c * (BSZ * DSZ) + idx];
    if (save0) ok0[idx] = s;
    u[idx] += s;
}

// ---------------------------------------------------------------------------
// p_vocab split-c: grid (125, P). y==0 writes (with bias) to out; y>0 to pvp.
__global__ __launch_bounds__(256) void k_pvocab2(const float* __restrict__ u0,
                                                 const float* __restrict__ ok0,
                                                 const float* __restrict__ W1w,
                                                 const float* __restrict__ W1b,
                                                 float* __restrict__ out_pv,
                                                 float* __restrict__ pvp,
                                                 int cshift) {
    int CPB = 1 << cshift;                 // 128 (P=4) or 256 (P=2)
    int c0 = blockIdx.y << cshift;
    float* dest = (blockIdx.y == 0) ? out_pv : (pvp + (size_t)(blockIdx.y - 1) * PVN);
    __shared__ float catL[BSZ * 256];
    int t = threadIdx.x;
    for (int i = t; i < BSZ * CPB; i += 256) {
        int b = i >> cshift, c = i & (CPB - 1);
        int gc = c0 + c;
        catL[b * CPB + c] = (gc < DSZ) ? u0[b * DSZ + gc] : ok0[b * DSZ + gc - DSZ];
    }
    __syncthreads();
    int vq = t & 63, bg = t >> 6;
    int v0 = blockIdx.x * 256 + vq * 4;
    int b0 = bg * 8;
    float acc[4][8] = {};
    for (int c = 0; c < CPB; c += 4) {
        float4 w0 = *(const float4*)(W1w + (size_t)(v0 + 0) * 512 + c0 + c);
        float4 w1 = *(const float4*)(W1w + (size_t)(v0 + 1) * 512 + c0 + c);
        float4 w2 = *(const float4*)(W1w + (size_t)(v0 + 2) * 512 + c0 + c);
        float4 w3 = *(const float4*)(W1w + (size_t)(v0 + 3) * 512 + c0 + c);
#pragma unroll
        for (int j = 0; j < 8; ++j) {
            float4 uv = *(const float4*)(&catL[(b0 + j) * CPB + c]);
            acc[0][j] += w0.x * uv.x + w0.y * uv.y + w0.z * uv.z + w0.w * uv.w;
            acc[1][j] += w1.x * uv.x + w1.y * uv.y + w1.z * uv.z + w1.w * uv.w;
            acc[2][j] += w2.x * uv.x + w2.y * uv.y + w2.z * uv.z + w2.w * uv.w;
            acc[3][j] += w3.x * uv.x + w3.y * uv.y + w3.z * uv.z + w3.w * uv.w;
        }
    }
    int addb = (blockIdx.y == 0);
#pragma unroll
    for (int j = 0; j < 8; ++j) {
        float4 o;
        o.x = acc[0][j]; o.y = acc[1][j]; o.z = acc[2][j]; o.w = acc[3][j];
        if (addb) { o.x += W1b[v0]; o.y += W1b[v0 + 1]; o.z += W1b[v0 + 2]; o.w += W1b[v0 + 3]; }
        *(float4*)(dest + (size_t)(b0 + j) * VSZ + v0) = o;
    }
}

// out_pv[i] += sum of np partials
__global__ void k_pvreduce(float* __restrict__ out_pv, const float* __restrict__ pvp,
                           int np) {
    int i = blockIdx.x * 256 + threadIdx.x;
    float s = out_pv[i];
    for (int k = 0; k < np; ++k) s += pvp[(size_t)k * PVN + i];
    out_pv[i] = s;
}

// ---------------------------------------------------------------------------
extern "C" void kernel_launch(void* const* d_in, const int* in_sizes, int n_in,
                              void* d_out, int out_size, void* d_ws, size_t ws_size,
                              hipStream_t stream) {
    const int*   story  = (const int*)d_in[0];
    const int*   encq   = (const int*)d_in[1];
    const float* lasth  = (const float*)d_in[2];
    const float* C      = (const float*)d_in[3];
    const float* postab = (const float*)d_in[4];
    const float* W1w    = (const float*)d_in[5];
    const float* W1b    = (const float*)d_in[6];
    const float* gwih   = (const float*)d_in[7];
    const float* gwhh   = (const float*)d_in[8];
    const float* gbih   = (const float*)d_in[9];
    const float* gbhh   = (const float*)d_in[10];

    float* out = (float*)d_out;
    float* wsf = (float*)d_ws;
    int*   pos  = (int*)d_ws;
    float* u    = wsf + OFF_U;
    float* u0   = wsf + OFF_U0;
    float* ok0  = wsf + OFF_OK0;
    float* pp   = wsf + OFF_PP;
    float* prob = wsf + OFF_PROB;
    float* part = wsf + OFF_PART;
    float* projA = wsf + OFF_PROJA;

    int big = (ws_size >= (size_t)END_BIG * 4);
    int S = big ? 2 : 1;                         // proj c-split
    int P = big ? 4 : 2;                         // pvocab c-split
    float* projB = big ? (wsf + OFF_PROJB) : projA;   // unused when S==1
    float* pvp   = big ? (wsf + OFF_PVP)   : projA;   // small: alias freed proj
    int proj_cshift = big ? 7 : 8;
    int pv_cshift   = big ? 7 : 8;

    k_positions<<<BSZ, MSZ, 0, stream>>>(story, pos);
    k_gru<<<BSZ, DSZ, 0, stream>>>(encq, lasth, C, gwih, gwhh, gbih, gbhh,
                                   u, u0, out + OUT_HID);
    k_posproj<<<(PSZ * BSZ + 255) / 256, 256, 0, stream>>>(postab, u, pp);

    for (int hop = 0; hop < HOPS; ++hop) {
        k_proj2<<<dim3(VSZ / 256, S), 256, 0, stream>>>(C + (size_t)hop * VD, u,
                                                        projA, projB, proj_cshift);
        int do_sm = (hop < 2);
        k_attend<<<BSZ, MSZ, 0, stream>>>(story, pos, projA, projB, pp, prob,
                                          out, S, hop, do_sm);
        if (hop == 2) break;   // hop2 only needs logits
        k_okpart2<<<dim3(8, BSZ), 256, 0, stream>>>(story, prob,
                                                    C + (size_t)(hop + 1) * VD, part);
        k_okreduce2<<<BSZ * DSZ / 256, 256, 0, stream>>>(part, u, ok0, hop == 0 ? 1 : 0);
        if (hop == 0) {
            k_pvocab2<<<dim3(VSZ / 256, P), 256, 0, stream>>>(u0, ok0, W1w, W1b,
                                                              out + OUT_PV, pvp, pv_cshift);
            k_pvreduce<<<PVN / 256, 256, 0, stream>>>(out + OUT_PV, pvp, P - 1);
        }
    }
}

// Round 3
// 236.811 us; speedup vs baseline: 1.6822x; 1.2728x over previous
//
#include <hip/hip_runtime.h>
#include <hip/hip_bf16.h>

#define VSZ 32000
#define DSZ 256
#define BSZ 32
#define MSZ 1024
#define TSZ 4
#define PSZ 1025
#define HOPS 3
#define VD (VSZ * DSZ)

// Workspace layout (float offsets)
#define OFF_POS   0                         // int[B*M]
#define OFF_U     32768
#define OFF_U0    40960
#define OFF_OK0   49152
#define OFF_PP    57344                     // 1025*32 = 32800
#define OFF_PROB  90144                     // 32768
#define OFF_PART  122912                    // 128*B*D = 1,048,576
#define OFF_PROJ  1171488                   // V*B = 1,024,000
#define WS_END    2195488                   // ~8.8 MB

// Output layout (floats): prob_lg [B,M] | p_vocab [B,V] | hidden [1,B,D]
#define OUT_PV    (BSZ * MSZ)
#define OUT_HID   (OUT_PV + BSZ * VSZ)

// ---------------------------------------------------------------------------
// positions: ballot-based segmented scan. 32 blocks x 1024 threads.
__global__ void k_positions(const int* __restrict__ story, int* __restrict__ pos) {
    int b = blockIdx.x;
    int m = threadIdx.x;
    __shared__ int wsum[16];
    int tok0 = story[(m * BSZ + b) * TSZ];
    int flag = (tok0 != 0) ? 1 : 0;
    unsigned long long mask = __ballot(flag);
    int lane = m & 63, wid = m >> 6;
    int pfx = __popcll(mask & ((1ULL << lane) - 1ULL));
    if (lane == 63) wsum[wid] = pfx + flag;
    __syncthreads();
    if (m == 0) {
        int run = 0;
        for (int i = 0; i < 16; ++i) { int v = wsum[i]; wsum[i] = run; run += v; }
    }
    __syncthreads();
    int incl = wsum[wid] + pfx + flag;
    pos[b * MSZ + m] = flag ? incl : 0;
}

// ---------------------------------------------------------------------------
// GRU step. One block per b, 256 threads (one per d).
__global__ void k_gru(const int* __restrict__ enc_query,
                      const float* __restrict__ last_hidden,
                      const float* __restrict__ C0,
                      const float* __restrict__ w_ih, const float* __restrict__ w_hh,
                      const float* __restrict__ b_ih, const float* __restrict__ b_hh,
                      float* __restrict__ u, float* __restrict__ u0,
                      float* __restrict__ hidden_out) {
    int b = blockIdx.x;
    int d = threadIdx.x;
    __shared__ float xs[DSZ], hs[DSZ];
    int q = enc_query[b];
    xs[d] = C0[(size_t)q * DSZ + d];
    hs[d] = last_hidden[b * DSZ + d];
    __syncthreads();
    float gi[3], gh[3];
#pragma unroll
    for (int g = 0; g < 3; ++g) {
        const float* wi = w_ih + (size_t)(g * DSZ + d) * DSZ;
        const float* wh = w_hh + (size_t)(g * DSZ + d) * DSZ;
        float a = 0.f, c = 0.f;
        for (int j = 0; j < DSZ; j += 4) {
            float4 wv = *(const float4*)(wi + j);
            a += wv.x * xs[j] + wv.y * xs[j + 1] + wv.z * xs[j + 2] + wv.w * xs[j + 3];
            float4 hv = *(const float4*)(wh + j);
            c += hv.x * hs[j] + hv.y * hs[j + 1] + hv.z * hs[j + 2] + hv.w * hs[j + 3];
        }
        gi[g] = a + b_ih[g * DSZ + d];
        gh[g] = c + b_hh[g * DSZ + d];
    }
    float r = 1.f / (1.f + expf(-(gi[0] + gh[0])));
    float z = 1.f / (1.f + expf(-(gi[1] + gh[1])));
    float n = tanhf(gi[2] + r * gh[2]);
    float hn = (1.f - z) * n + z * hs[d];
    int idx = b * DSZ + d;
    u[idx] = hn;
    u0[idx] = hn;
    hidden_out[idx] = hn;
}

// ---------------------------------------------------------------------------
// pp[p][b] = dot(pos_table[p], u[b])
__global__ void k_posproj(const float* __restrict__ pos_table,
                          const float* __restrict__ u, float* __restrict__ pp) {
    int idx = blockIdx.x * 256 + threadIdx.x;
    if (idx >= PSZ * BSZ) return;
    int p = idx >> 5;
    int b = idx & 31;
    const float* row = pos_table + (size_t)p * DSZ;
    const float* ub = u + b * DSZ;
    float acc = 0.f;
    for (int j = 0; j < DSZ; j += 4) {
        float4 rv = *(const float4*)(row + j);
        float4 uv = *(const float4*)(ub + j);
        acc += rv.x * uv.x + rv.y * uv.y + rv.z * uv.z + rv.w * uv.w;
    }
    pp[idx] = acc;
}

// ---------------------------------------------------------------------------
// proj[v][b] = dot(C[h][v], u[b]).  Row-per-lane streamer.
// Grid 250 blocks x 256 thr. Block: 128 rows (lane + {0,64}), tile 2v x 8b.
// Lanes read 64B/row/step -> full cache lines, 16 f4 in flight w/ prefetch.
__global__ __launch_bounds__(256) void k_proj3(const float* __restrict__ Ct,
                                               const float* __restrict__ u,
                                               float* __restrict__ proj) {
    __shared__ float xL[BSZ][DSZ];           // 32 KB
    int t = threadIdx.x;
    const float4* u4 = (const float4*)u;
    for (int i = t; i < BSZ * (DSZ / 4); i += 256) {
        int b = i >> 6, c4 = i & 63;
        *(float4*)&xL[b][c4 * 4] = u4[b * 64 + c4];
    }
    __syncthreads();
    int lane = t & 63, bg = t >> 6;          // bg wave-uniform
    int b0 = bg * 8;
    int v0 = blockIdx.x * 128 + lane;        // rows v0, v0+64
    const float* w0p = Ct + (size_t)v0 * DSZ;
    const float* w1p = w0p + (size_t)64 * DSZ;
    float acc0[8] = {}, acc1[8] = {};
    float4 wa[4], wb[4], na[4], nb[4];
#pragma unroll
    for (int k = 0; k < 4; ++k) {
        wa[k] = *(const float4*)(w0p + k * 4);
        wb[k] = *(const float4*)(w1p + k * 4);
    }
    for (int s = 0; s < DSZ / 16; ++s) {
        if (s < DSZ / 16 - 1) {
            int cn = (s + 1) * 16;
#pragma unroll
            for (int k = 0; k < 4; ++k) {
                na[k] = *(const float4*)(w0p + cn + k * 4);
                nb[k] = *(const float4*)(w1p + cn + k * 4);
            }
        }
        int c = s * 16;
#pragma unroll
        for (int j = 0; j < 8; ++j) {
            const float* xp = &xL[b0 + j][c];
#pragma unroll
            for (int k = 0; k < 4; ++k) {
                float4 xv = *(const float4*)(xp + k * 4);
                acc0[j] += wa[k].x * xv.x + wa[k].y * xv.y + wa[k].z * xv.z + wa[k].w * xv.w;
                acc1[j] += wb[k].x * xv.x + wb[k].y * xv.y + wb[k].z * xv.z + wb[k].w * xv.w;
            }
        }
#pragma unroll
        for (int k = 0; k < 4; ++k) { wa[k] = na[k]; wb[k] = nb[k]; }
    }
#pragma unroll
    for (int j = 0; j < 8; ++j) {
        proj[(size_t)v0 * BSZ + b0 + j] = acc0[j];
        proj[(size_t)(v0 + 64) * BSZ + b0 + j] = acc1[j];
    }
}

// ---------------------------------------------------------------------------
// Fused scores (+positional at hop0) + softmax. 32 blocks x 1024 threads.
__global__ void k_attend2(const int* __restrict__ story, const int* __restrict__ pos,
                          const float* __restrict__ proj, const float* __restrict__ pp,
                          float* __restrict__ prob, float* __restrict__ outlg, int hop) {
    int b = blockIdx.x;
    int m = threadIdx.x;
    __shared__ float red[16];
    int4 st = *(const int4*)&story[(m * BSZ + b) * TSZ];
    float s = proj[(size_t)st.x * BSZ + b] + proj[(size_t)st.y * BSZ + b] +
              proj[(size_t)st.z * BSZ + b] + proj[(size_t)st.w * BSZ + b];
    if (hop == 0) s += pp[pos[b * MSZ + m] * BSZ + b];
    if (hop == 2) { outlg[b * MSZ + m] = s; return; }
    float mx = s;
#pragma unroll
    for (int o = 32; o > 0; o >>= 1) mx = fmaxf(mx, __shfl_xor(mx, o, 64));
    int wid = m >> 6, lane = m & 63;
    if (lane == 0) red[wid] = mx;
    __syncthreads();
    if (m == 0) {
        float a = red[0];
        for (int i = 1; i < 16; ++i) a = fmaxf(a, red[i]);
        red[0] = a;
    }
    __syncthreads();
    float bm = red[0];
    __syncthreads();
    float e = expf(s - bm);
    float sm = e;
#pragma unroll
    for (int o = 32; o > 0; o >>= 1) sm += __shfl_xor(sm, o, 64);
    if (lane == 0) red[wid] = sm;
    __syncthreads();
    if (m == 0) {
        float a = 0.f;
        for (int i = 0; i < 16; ++i) a += red[i];
        red[0] = a;
    }
    __syncthreads();
    prob[b * MSZ + m] = e / red[0];
}

// ---------------------------------------------------------------------------
// o_k partials: grid (32 mc, 32 b), 256 thr = 64 d-quads x 4 m-subgroups.
// story/prob loads are wave-uniform (s_load broadcast); pipelined 1 ahead.
__global__ __launch_bounds__(256) void k_okpart3(const int* __restrict__ story,
                                                 const float* __restrict__ prob,
                                                 const float* __restrict__ Ct,
                                                 float* __restrict__ part) {
    int mc = blockIdx.x;
    int b = blockIdx.y;
    int dl = threadIdx.x & 63;
    int ms = threadIdx.x >> 6;
    int mbase = mc * 32 + ms * 8;
    float4 acc = make_float4(0.f, 0.f, 0.f, 0.f);
    int4 st = *(const int4*)&story[(mbase * BSZ + b) * TSZ];
    float pw = prob[b * MSZ + mbase];
#pragma unroll
    for (int i = 0; i < 8; ++i) {
        int4 stc = st; float pwc = pw;
        if (i < 7) {
            st = *(const int4*)&story[((mbase + i + 1) * BSZ + b) * TSZ];
            pw = prob[b * MSZ + mbase + i + 1];
        }
        float4 a0 = ((const float4*)&Ct[(size_t)stc.x * DSZ])[dl];
        float4 a1 = ((const float4*)&Ct[(size_t)stc.y * DSZ])[dl];
        float4 a2 = ((const float4*)&Ct[(size_t)stc.z * DSZ])[dl];
        float4 a3 = ((const float4*)&Ct[(size_t)stc.w * DSZ])[dl];
        acc.x += pwc * (a0.x + a1.x + a2.x + a3.x);
        acc.y += pwc * (a0.y + a1.y + a2.y + a3.y);
        acc.z += pwc * (a0.z + a1.z + a2.z + a3.z);
        acc.w += pwc * (a0.w + a1.w + a2.w + a3.w);
    }
    int chunk = mc * 4 + ms;
    *(float4*)&part[((size_t)(chunk * BSZ) + b) * DSZ + dl * 4] = acc;
}

// reduce 128 partial chunks -> o_k; u += o_k; save ok0 at hop 0.
__global__ void k_okreduce3(const float* __restrict__ part, float* __restrict__ u,
                            float* __restrict__ ok0, int save0) {
    int idx = blockIdx.x * 256 + threadIdx.x;   // B*D = 8192
    float s = 0.f;
    for (int c = 0; c < 128; ++c) s += part[(size_t)c * (BSZ * DSZ) + idx];
    if (save0) ok0[idx] = s;
    u[idx] += s;
}

// ---------------------------------------------------------------------------
// p_vocab row-per-lane streamer: grid 250 x 256 thr, 128 rows/block, 2v x 8b.
__global__ __launch_bounds__(256) void k_pvocab3(const float* __restrict__ u0,
                                                 const float* __restrict__ ok0,
                                                 const float* __restrict__ W1w,
                                                 const float* __restrict__ W1b,
                                                 float* __restrict__ out_pv) {
    __shared__ float xL[BSZ][2 * DSZ];       // 64 KB
    int t = threadIdx.x;
    const float4* u04 = (const float4*)u0;
    const float4* ok4 = (const float4*)ok0;
    for (int i = t; i < BSZ * 128; i += 256) {
        int b = i >> 7, c4 = i & 127;
        float4 v = (c4 < 64) ? u04[b * 64 + c4] : ok4[b * 64 + (c4 - 64)];
        *(float4*)&xL[b][c4 * 4] = v;
    }
    __syncthreads();
    int lane = t & 63, bg = t >> 6;
    int b0 = bg * 8;
    int v0 = blockIdx.x * 128 + lane;        // rows v0, v0+64
    const float* w0p = W1w + (size_t)v0 * 512;
    const float* w1p = w0p + (size_t)64 * 512;
    float acc0[8] = {}, acc1[8] = {};
    float4 wa[4], wb[4], na[4], nb[4];
#pragma unroll
    for (int k = 0; k < 4; ++k) {
        wa[k] = *(const float4*)(w0p + k * 4);
        wb[k] = *(const float4*)(w1p + k * 4);
    }
    for (int s = 0; s < 32; ++s) {
        if (s < 31) {
            int cn = (s + 1) * 16;
#pragma unroll
            for (int k = 0; k < 4; ++k) {
                na[k] = *(const float4*)(w0p + cn + k * 4);
                nb[k] = *(const float4*)(w1p + cn + k * 4);
            }
        }
        int c = s * 16;
#pragma unroll
        for (int j = 0; j < 8; ++j) {
            const float* xp = &xL[b0 + j][c];
#pragma unroll
            for (int k = 0; k < 4; ++k) {
                float4 xv = *(const float4*)(xp + k * 4);
                acc0[j] += wa[k].x * xv.x + wa[k].y * xv.y + wa[k].z * xv.z + wa[k].w * xv.w;
                acc1[j] += wb[k].x * xv.x + wb[k].y * xv.y + wb[k].z * xv.z + wb[k].w * xv.w;
            }
        }
#pragma unroll
        for (int k = 0; k < 4; ++k) { wa[k] = na[k]; wb[k] = nb[k]; }
    }
    float bias0 = W1b[v0], bias1 = W1b[v0 + 64];
#pragma unroll
    for (int j = 0; j < 8; ++j) {
        out_pv[(size_t)(b0 + j) * VSZ + v0] = acc0[j] + bias0;
        out_pv[(size_t)(b0 + j) * VSZ + v0 + 64] = acc1[j] + bias1;
    }
}

// ---------------------------------------------------------------------------
extern "C" void kernel_launch(void* const* d_in, const int* in_sizes, int n_in,
                              void* d_out, int out_size, void* d_ws, size_t ws_size,
                              hipStream_t stream) {
    const int*   story  = (const int*)d_in[0];
    const int*   encq   = (const int*)d_in[1];
    const float* lasth  = (const float*)d_in[2];
    const float* C      = (const float*)d_in[3];
    const float* postab = (const float*)d_in[4];
    const float* W1w    = (const float*)d_in[5];
    const float* W1b    = (const float*)d_in[6];
    const float* gwih   = (const float*)d_in[7];
    const float* gwhh   = (const float*)d_in[8];
    const float* gbih   = (const float*)d_in[9];
    const float* gbhh   = (const float*)d_in[10];

    float* out = (float*)d_out;
    float* wsf = (float*)d_ws;
    int*   pos  = (int*)d_ws;
    float* u    = wsf + OFF_U;
    float* u0   = wsf + OFF_U0;
    float* ok0  = wsf + OFF_OK0;
    float* pp   = wsf + OFF_PP;
    float* prob = wsf + OFF_PROB;
    float* part = wsf + OFF_PART;
    float* proj = wsf + OFF_PROJ;

    k_positions<<<BSZ, MSZ, 0, stream>>>(story, pos);
    k_gru<<<BSZ, DSZ, 0, stream>>>(encq, lasth, C, gwih, gwhh, gbih, gbhh,
                                   u, u0, out + OUT_HID);
    k_posproj<<<(PSZ * BSZ + 255) / 256, 256, 0, stream>>>(postab, u, pp);

    for (int hop = 0; hop < HOPS; ++hop) {
        k_proj3<<<VSZ / 128, 256, 0, stream>>>(C + (size_t)hop * VD, u, proj);
        k_attend2<<<BSZ, MSZ, 0, stream>>>(story, pos, proj, pp, prob, out, hop);
        if (hop == 2) break;   // hop2 only needs logits
        k_okpart3<<<dim3(32, BSZ), 256, 0, stream>>>(story, prob,
                                                     C + (size_t)(hop + 1) * VD, part);
        k_okreduce3<<<BSZ * DSZ / 256, 256, 0, stream>>>(part, u, ok0, hop == 0 ? 1 : 0);
        if (hop == 0) {
            k_pvocab3<<<VSZ / 128, 256, 0, stream>>>(u0, ok0, W1w, W1b, out + OUT_PV);
        }
    }
}